// Round 12
// baseline (250.777 us; speedup 1.0000x reference)
//
#include <hip/hip_runtime.h>

typedef unsigned short u16;
typedef __attribute__((ext_vector_type(8))) short short8;
typedef __attribute__((ext_vector_type(8))) unsigned short ushort8v;
typedef __attribute__((ext_vector_type(4))) float f32x4;

#define B_ 8
#define T_ 256
#define U_ 64
#define E_ 512
#define J_ 640
#define V_ 1024
#define NT 20

__device__ __forceinline__ u16 f2bf(float f) {
  unsigned int u = __float_as_uint(f);
  u += 0x7fffu + ((u >> 16) & 1u);   // round-to-nearest-even
  return (u16)(u >> 16);
}

__device__ __forceinline__ void gload16(const void* g, void* l) {
  __builtin_amdgcn_global_load_lds((const __attribute__((address_space(1))) void*)g,
                                   (__attribute__((address_space(3))) void*)l,
                                   16, 0, 0);
}

// ---------------- fused cast fp32 -> bf16 for all 5 inputs (dsts contiguous in ws) --------
__global__ __launch_bounds__(256) void cast5_k(const float4* __restrict__ s0,
                                               const float4* __restrict__ s1,
                                               const float4* __restrict__ s2,
                                               const float4* __restrict__ s3,
                                               const float4* __restrict__ s4,
                                               ushort4* __restrict__ dst) {
  int i = blockIdx.x * 256 + threadIdx.x;
  const int st = gridDim.x * 256;
  for (; i < 655360; i += st) {
    const float4* s; int off;
    if (i < 262144)      { s = s0; off = 0; }
    else if (i < 327680) { s = s1; off = 262144; }
    else if (i < 409600) { s = s2; off = 327680; }
    else if (i < 491520) { s = s3; off = 409600; }
    else                 { s = s4; off = 491520; }
    float4 v = s[i - off];
    ushort4 o;
    o.x = f2bf(v.x); o.y = f2bf(v.y); o.z = f2bf(v.z); o.w = f2bf(v.w);
    dst[i] = o;
  }
}

// ---------------- projection GEMM (small, latency-tolerant) ----------------
__global__ __launch_bounds__(256) void proj_k(const u16* __restrict__ X,
                                              const u16* __restrict__ W,
                                              float* __restrict__ C) {
  __shared__ __align__(16) u16 As[128 * 32];
  __shared__ __align__(16) u16 Bs[128 * 32];
  const int tid = threadIdx.x;
  const int w = tid >> 6, lane = tid & 63;
  const int wr = w >> 1, wc = w & 1;
  const int m0 = blockIdx.x * 128, n0 = blockIdx.y * 128;
  const int lr = lane & 15, lk = lane >> 4;
  const int r4 = tid >> 2, kq = tid & 3;

  f32x4 acc[4][4] = {};

  for (int ks = 0; ks < E_ / 32; ++ks) {
    const int k0 = ks * 32;
    gload16(X + (size_t)(m0 + r4) * E_ + k0 + kq * 8, (char*)As + w * 1024);
    gload16(X + (size_t)(m0 + 64 + r4) * E_ + k0 + kq * 8, (char*)As + 4096 + w * 1024);
    gload16(W + (size_t)(n0 + r4) * E_ + k0 + kq * 8, (char*)Bs + w * 1024);
    gload16(W + (size_t)(n0 + 64 + r4) * E_ + k0 + kq * 8, (char*)Bs + 4096 + w * 1024);
    __syncthreads();
    short8 a[4], bb[4];
#pragma unroll
    for (int m = 0; m < 4; ++m)
      a[m] = *(const short8*)&As[(wr * 64 + m * 16 + lr) * 32 + lk * 8];
#pragma unroll
    for (int n = 0; n < 4; ++n)
      bb[n] = *(const short8*)&Bs[(wc * 64 + n * 16 + lr) * 32 + lk * 8];
#pragma unroll
    for (int m = 0; m < 4; ++m)
#pragma unroll
      for (int n = 0; n < 4; ++n)
        acc[m][n] = __builtin_amdgcn_mfma_f32_16x16x32_bf16(a[m], bb[n], acc[m][n], 0, 0, 0);
    __syncthreads();
  }

#pragma unroll
  for (int m = 0; m < 4; ++m) {
    const int row = m0 + wr * 64 + m * 16 + lk * 4;
#pragma unroll
    for (int n = 0; n < 4; ++n) {
      const int col = n0 + wc * 64 + n * 16 + lr;
#pragma unroll
      for (int i = 0; i < 4; ++i)
        C[(size_t)(row + i) * J_ + col] = acc[m][n][i];
    }
  }
}

// ---------------- Wo fragment pre-pack ----------------
// pk[((vt*20+ks)*4+nq)*512 + lane*8 + e] = Wo[vt*64+nq*16+(lane&15)][ks*32+(lane>>4)*8+e]
__global__ __launch_bounds__(256) void pack_k(const u16* __restrict__ Wo,
                                              u16* __restrict__ pk) {
  const int u = blockIdx.x * 256 + threadIdx.x;   // 81920 units of short8
  const int l = u & 63;
  int r = u >> 6;
  const int nq = r & 3;  r >>= 2;
  const int ks = r % 20;
  const int vt = r / 20;
  const int v = vt * 64 + nq * 16 + (l & 15);
  const int k = ks * 32 + (l >> 4) * 8;
  *(short8*)(pk + (size_t)u * 8) = *(const short8*)(Wo + (size_t)v * J_ + k);
}

// ---------------- fused joint v2: wave = 64 rows x 128 cols, swapped-operand epilogue ----
// Block = one (b,t). A-panel (64x640 bf16, silu-fused, XOR-swizzled) built once in LDS;
// one __syncthreads; then 20 K-steps of {8 coalesced B-frag loads + 4 A ds_reads + 32 MFMA},
// B and A distance-1 ping-pong (named sets). MFMA called as mfma(b,a) so lanes hold 4
// consecutive V values -> dwordx4 epilogue (32 stores/wave).
__global__ __launch_bounds__(512, 2) void fused2_k(const float* __restrict__ ep,
                                                   const float* __restrict__ pp,
                                                   const u16* __restrict__ pk,
                                                   float* __restrict__ out) {
  __shared__ __align__(16) u16 Alds[64 * 640];   // 80 KiB
  const int tid = threadIdx.x;
  const int w = tid >> 6, lane = tid & 63;
  const int lr = lane & 15, lk = lane >> 4;
  const int bt = blockIdx.x;                 // b*256 + t
  const int b = bt >> 8;
  const size_t m0 = (size_t)bt * 64;

  // B-frag bases: wave covers vt pair (w*2, w*2+1) = cols w*128 .. +127
  const u16* bp0 = pk + (size_t)(w * 2) * 40960 + lane * 8;
  const u16* bp1 = bp0 + 40960;

  short8 BE[8], BO[8], aE[4], aO[4];

#define BL(bF, ks)                                                             \
  do {                                                                         \
    _Pragma("unroll")                                                          \
    for (int nq = 0; nq < 4; ++nq) {                                           \
      bF[nq]     = *(const short8*)(bp0 + (ks) * 2048 + nq * 512);             \
      bF[4 + nq] = *(const short8*)(bp1 + (ks) * 2048 + nq * 512);             \
    }                                                                          \
  } while (0)

  BL(BE, 0);   // issue before phase 1: L2 latency hides under silu + barrier

  // ---- phase 1: build swizzled A-panel ----
  const float* eprow = ep + (size_t)bt * J_;
  const float* pbase = pp + (size_t)b * 64 * J_;
#pragma unroll
  for (int it = 0; it < 10; ++it) {
    const int unit = tid + it * 512;         // 5120 units = 64 rows x 80 chunks
    const int row = unit / 80;
    const int c = unit - row * 80;
    union { float4 v[2]; float f[8]; } Ee, Pp;
    Ee.v[0] = *(const float4*)(eprow + c * 8);
    Ee.v[1] = *(const float4*)(eprow + c * 8 + 4);
    Pp.v[0] = *(const float4*)(pbase + (size_t)row * J_ + c * 8);
    Pp.v[1] = *(const float4*)(pbase + (size_t)row * J_ + c * 8 + 4);
    union { ushort8v v; u16 s[8]; } R;
#pragma unroll
    for (int j = 0; j < 8; ++j) {
      float x = Ee.f[j] + Pp.f[j];
      R.s[j] = f2bf(x * __builtin_amdgcn_rcpf(1.0f + __expf(-x)));
    }
    *(ushort8v*)&Alds[row * 640 + ((c ^ (row & 7)) << 3)] = R.v;
  }
  __syncthreads();                            // the ONLY barrier

  // ---- phase 2: barrier-free K-pipelined GEMM ----
  const int rx = lr & 7;
  int arow[4];
#pragma unroll
  for (int mq = 0; mq < 4; ++mq) arow[mq] = (mq * 16 + lr) * 640;

#define AR(aF, ks)                                                             \
  do {                                                                         \
    _Pragma("unroll")                                                          \
    for (int mq = 0; mq < 4; ++mq)                                             \
      aF[mq] = *(const short8*)&Alds[arow[mq] + ((((ks) * 4 + lk) ^ rx) << 3)];\
  } while (0)

#define MM(aF, bF)                                                             \
  do {                                                                         \
    __builtin_amdgcn_s_setprio(1);                                             \
    _Pragma("unroll")                                                          \
    for (int mq = 0; mq < 4; ++mq)                                             \
      _Pragma("unroll")                                                        \
      for (int nq = 0; nq < 8; ++nq)                                           \
        acc[mq][nq] = __builtin_amdgcn_mfma_f32_16x16x32_bf16(bF[nq], aF[mq],  \
                                                              acc[mq][nq], 0, 0, 0); \
    __builtin_amdgcn_s_setprio(0);                                             \
  } while (0)

  f32x4 acc[4][8] = {};
  AR(aE, 0);

#pragma unroll 1
  for (int ks = 0; ks < NT; ks += 2) {
    BL(BO, ks + 1);
    AR(aO, ks + 1);
    MM(aE, BE);
    __builtin_amdgcn_sched_barrier(0);
    if (ks + 2 < NT) { BL(BE, ks + 2); AR(aE, ks + 2); }
    MM(aO, BO);
    __builtin_amdgcn_sched_barrier(0);
  }

  // ---- epilogue: swapped-operand layout -> lane holds out[u][v..v+3] -> dwordx4 ----
  const int col0 = w * 128;
#pragma unroll
  for (int mq = 0; mq < 4; ++mq) {
    const size_t row = m0 + mq * 16 + lr;
#pragma unroll
    for (int nq = 0; nq < 8; ++nq) {
      const int col = col0 + nq * 16 + lk * 4;
      *(float4*)&out[row * V_ + col] = *(float4*)&acc[mq][nq];
    }
  }
#undef AR
#undef BL
#undef MM
}

extern "C" void kernel_launch(void* const* d_in, const int* in_sizes, int n_in,
                              void* d_out, int out_size, void* d_ws, size_t ws_size,
                              hipStream_t stream) {
  const float* enc = (const float*)d_in[0];   // [8,256,512]
  const float* pred = (const float*)d_in[1];  // [8,64,512]
  const float* We = (const float*)d_in[2];    // [640,512]
  const float* Wp = (const float*)d_in[3];    // [640,512]
  const float* Wo = (const float*)d_in[4];    // [1024,640]
  float* out = (float*)d_out;                 // [8,256,64,1024]

  char* ws = (char*)d_ws;
  u16* enc_bf = (u16*)ws;                     // 2,097,152 B
  u16* pred_bf = (u16*)(ws + 2097152);        //   524,288 B
  u16* We_bf = (u16*)(ws + 2621440);          //   655,360 B
  u16* Wp_bf = (u16*)(ws + 3276800);          //   655,360 B
  u16* Wo_bf = (u16*)(ws + 3932160);          // 1,310,720 B -> ends 5,242,880
  float* ep = (float*)(ws + 5242880);         // 5,242,880 B  [2048][640]
  float* pp = (float*)(ws + 10485760);        // 1,310,720 B  [512][640] -> ends 11,796,480
  u16* Wo_pk = (u16*)(ws + 11796480);         // 1,310,720 B packed fragments -> ends 13,107,200

  cast5_k<<<2048, 256, 0, stream>>>((const float4*)enc, (const float4*)pred,
                                    (const float4*)We, (const float4*)Wp,
                                    (const float4*)Wo, (ushort4*)ws);

  proj_k<<<dim3(16, 5), 256, 0, stream>>>(enc_bf, We_bf, ep);  // [2048][640]
  proj_k<<<dim3(4, 5), 256, 0, stream>>>(pred_bf, Wp_bf, pp);  // [512][640]
  pack_k<<<320, 256, 0, stream>>>(Wo_bf, Wo_pk);

  fused2_k<<<2048, 512, 0, stream>>>(ep, pp, Wo_pk, out);
}

// Round 13
// 249.687 us; speedup vs baseline: 1.0044x; 1.0044x over previous
//
#include <hip/hip_runtime.h>

typedef unsigned short u16;
typedef __attribute__((ext_vector_type(8))) short short8;
typedef __attribute__((ext_vector_type(8))) unsigned short ushort8v;
typedef __attribute__((ext_vector_type(4))) float f32x4;

#define B_ 8
#define T_ 256
#define U_ 64
#define E_ 512
#define J_ 640
#define V_ 1024
#define NT 20

__device__ __forceinline__ u16 f2bf(float f) {
  unsigned int u = __float_as_uint(f);
  u += 0x7fffu + ((u >> 16) & 1u);   // round-to-nearest-even
  return (u16)(u >> 16);
}

__device__ __forceinline__ void gload16(const void* g, void* l) {
  __builtin_amdgcn_global_load_lds((const __attribute__((address_space(1))) void*)g,
                                   (__attribute__((address_space(3))) void*)l,
                                   16, 0, 0);
}

// ---------------- fused cast fp32 -> bf16 for all 5 inputs (dsts contiguous in ws) --------
__global__ __launch_bounds__(256) void cast5_k(const float4* __restrict__ s0,
                                               const float4* __restrict__ s1,
                                               const float4* __restrict__ s2,
                                               const float4* __restrict__ s3,
                                               const float4* __restrict__ s4,
                                               ushort4* __restrict__ dst) {
  int i = blockIdx.x * 256 + threadIdx.x;
  const int st = gridDim.x * 256;
  for (; i < 655360; i += st) {
    const float4* s; int off;
    if (i < 262144)      { s = s0; off = 0; }
    else if (i < 327680) { s = s1; off = 262144; }
    else if (i < 409600) { s = s2; off = 327680; }
    else if (i < 491520) { s = s3; off = 409600; }
    else                 { s = s4; off = 491520; }
    float4 v = s[i - off];
    ushort4 o;
    o.x = f2bf(v.x); o.y = f2bf(v.y); o.z = f2bf(v.z); o.w = f2bf(v.w);
    dst[i] = o;
  }
}

// ---------------- projection GEMM (small, latency-tolerant) ----------------
__global__ __launch_bounds__(256) void proj_k(const u16* __restrict__ X,
                                              const u16* __restrict__ W,
                                              float* __restrict__ C) {
  __shared__ __align__(16) u16 As[128 * 32];
  __shared__ __align__(16) u16 Bs[128 * 32];
  const int tid = threadIdx.x;
  const int w = tid >> 6, lane = tid & 63;
  const int wr = w >> 1, wc = w & 1;
  const int m0 = blockIdx.x * 128, n0 = blockIdx.y * 128;
  const int lr = lane & 15, lk = lane >> 4;
  const int r4 = tid >> 2, kq = tid & 3;

  f32x4 acc[4][4] = {};

  for (int ks = 0; ks < E_ / 32; ++ks) {
    const int k0 = ks * 32;
    gload16(X + (size_t)(m0 + r4) * E_ + k0 + kq * 8, (char*)As + w * 1024);
    gload16(X + (size_t)(m0 + 64 + r4) * E_ + k0 + kq * 8, (char*)As + 4096 + w * 1024);
    gload16(W + (size_t)(n0 + r4) * E_ + k0 + kq * 8, (char*)Bs + w * 1024);
    gload16(W + (size_t)(n0 + 64 + r4) * E_ + k0 + kq * 8, (char*)Bs + 4096 + w * 1024);
    __syncthreads();
    short8 a[4], bb[4];
#pragma unroll
    for (int m = 0; m < 4; ++m)
      a[m] = *(const short8*)&As[(wr * 64 + m * 16 + lr) * 32 + lk * 8];
#pragma unroll
    for (int n = 0; n < 4; ++n)
      bb[n] = *(const short8*)&Bs[(wc * 64 + n * 16 + lr) * 32 + lk * 8];
#pragma unroll
    for (int m = 0; m < 4; ++m)
#pragma unroll
      for (int n = 0; n < 4; ++n)
        acc[m][n] = __builtin_amdgcn_mfma_f32_16x16x32_bf16(a[m], bb[n], acc[m][n], 0, 0, 0);
    __syncthreads();
  }

#pragma unroll
  for (int m = 0; m < 4; ++m) {
    const int row = m0 + wr * 64 + m * 16 + lk * 4;
#pragma unroll
    for (int n = 0; n < 4; ++n) {
      const int col = n0 + wc * 64 + n * 16 + lr;
#pragma unroll
      for (int i = 0; i < 4; ++i)
        C[(size_t)(row + i) * J_ + col] = acc[m][n][i];
    }
  }
}

// ---------------- Wo fragment pre-pack ----------------
// pk[((vt*20+ks)*4+nq)*512 + lane*8 + e] = Wo[vt*64+nq*16+(lane&15)][ks*32+(lane>>4)*8+e]
__global__ __launch_bounds__(256) void pack_k(const u16* __restrict__ Wo,
                                              u16* __restrict__ pk) {
  const int u = blockIdx.x * 256 + threadIdx.x;   // 81920 units of short8
  const int l = u & 63;
  int r = u >> 6;
  const int nq = r & 3;  r >>= 2;
  const int ks = r % 20;
  const int vt = r / 20;
  const int v = vt * 64 + nq * 16 + (l & 15);
  const int k = ks * 32 + (l >> 4) * 8;
  *(short8*)(pk + (size_t)u * 8) = *(const short8*)(Wo + (size_t)v * J_ + k);
}

// ---------------- fused joint v3: 1024 threads, 16 waves, wave = 64 rows x 64 cols ------
// Block = one (b,t). A-panel (64x640 bf16, silu-fused, XOR-swizzled) in LDS (80 KiB),
// built by 1024 threads; one __syncthreads; then each wave runs its own barrier-free
// K-loop over its vt chunk: {4 coalesced 1KB B-frag loads + 4 A ds_reads + 16 MFMA},
// B ping-pong dist-1 (first set prefetched before silu). VGPR <= 128 -> 4 waves/SIMD.
// mfma(b,a) swapped operands -> lane holds 4 consecutive V -> dwordx4 epilogue.
__global__ __launch_bounds__(1024, 1) void fused3_k(const float* __restrict__ ep,
                                                    const float* __restrict__ pp,
                                                    const u16* __restrict__ pk,
                                                    float* __restrict__ out) {
  __shared__ __align__(16) u16 Alds[64 * 640];   // 80 KiB
  const int tid = threadIdx.x;
  const int w = tid >> 6, lane = tid & 63;       // w = vt chunk 0..15
  const int lr = lane & 15, lk = lane >> 4;
  const int bt = blockIdx.x;                     // b*256 + t
  const int b = bt >> 8;
  const size_t m0 = (size_t)bt * 64;

  const u16* bp = pk + (size_t)w * 40960 + lane * 8;

  short8 BE[4], BO[4], a[4];

#define BL(bF, ks)                                                             \
  do {                                                                         \
    _Pragma("unroll")                                                          \
    for (int nq = 0; nq < 4; ++nq)                                             \
      bF[nq] = *(const short8*)(bp + (ks) * 2048 + nq * 512);                  \
  } while (0)

  BL(BE, 0);   // prefetch before silu: L2 latency hides under phase 1

  // ---- phase 1: build swizzled A-panel (5 units/thread) ----
  const float* eprow = ep + (size_t)bt * J_;
  const float* pbase = pp + (size_t)b * 64 * J_;
#pragma unroll
  for (int it = 0; it < 5; ++it) {
    const int unit = tid + it * 1024;        // 5120 units = 64 rows x 80 chunks
    const int row = unit / 80;
    const int c = unit - row * 80;
    union { float4 v[2]; float f[8]; } Ee, Pp;
    Ee.v[0] = *(const float4*)(eprow + c * 8);
    Ee.v[1] = *(const float4*)(eprow + c * 8 + 4);
    Pp.v[0] = *(const float4*)(pbase + (size_t)row * J_ + c * 8);
    Pp.v[1] = *(const float4*)(pbase + (size_t)row * J_ + c * 8 + 4);
    union { ushort8v v; u16 s[8]; } R;
#pragma unroll
    for (int j = 0; j < 8; ++j) {
      float x = Ee.f[j] + Pp.f[j];
      R.s[j] = f2bf(x * __builtin_amdgcn_rcpf(1.0f + __expf(-x)));
    }
    *(ushort8v*)&Alds[row * 640 + ((c ^ (row & 7)) << 3)] = R.v;
  }
  __syncthreads();                            // the ONLY barrier

  // ---- phase 2: per-wave barrier-free K-loop ----
  const int rx = lr & 7;

#define AR(ks)                                                                 \
  do {                                                                         \
    _Pragma("unroll")                                                          \
    for (int mq = 0; mq < 4; ++mq)                                             \
      a[mq] = *(const short8*)&Alds[(mq * 16 + lr) * 640 +                     \
                                    ((((ks) * 4 + lk) ^ rx) << 3)];            \
  } while (0)

#define MM(bF)                                                                 \
  do {                                                                         \
    __builtin_amdgcn_s_setprio(1);                                             \
    _Pragma("unroll")                                                          \
    for (int mq = 0; mq < 4; ++mq)                                             \
      _Pragma("unroll")                                                        \
      for (int nq = 0; nq < 4; ++nq)                                           \
        acc[mq][nq] = __builtin_amdgcn_mfma_f32_16x16x32_bf16(bF[nq], a[mq],   \
                                                              acc[mq][nq], 0, 0, 0); \
    __builtin_amdgcn_s_setprio(0);                                             \
  } while (0)

  f32x4 acc[4][4] = {};

#pragma unroll 1
  for (int ks = 0; ks < NT; ks += 2) {
    AR(ks);
    BL(BO, ks + 1);
    MM(BE);
    __builtin_amdgcn_sched_barrier(0);
    AR(ks + 1);
    if (ks + 2 < NT) BL(BE, ks + 2);
    MM(BO);
    __builtin_amdgcn_sched_barrier(0);
  }

  // ---- epilogue: swapped-operand layout -> lane holds out[u][v..v+3] -> dwordx4 ----
#pragma unroll
  for (int mq = 0; mq < 4; ++mq) {
    const size_t row = m0 + mq * 16 + lr;
#pragma unroll
    for (int nq = 0; nq < 4; ++nq) {
      const int col = w * 64 + nq * 16 + lk * 4;
      *(float4*)&out[row * V_ + col] = *(float4*)&acc[mq][nq];
    }
  }
#undef AR
#undef BL
#undef MM
}

extern "C" void kernel_launch(void* const* d_in, const int* in_sizes, int n_in,
                              void* d_out, int out_size, void* d_ws, size_t ws_size,
                              hipStream_t stream) {
  const float* enc = (const float*)d_in[0];   // [8,256,512]
  const float* pred = (const float*)d_in[1];  // [8,64,512]
  const float* We = (const float*)d_in[2];    // [640,512]
  const float* Wp = (const float*)d_in[3];    // [640,512]
  const float* Wo = (const float*)d_in[4];    // [1024,640]
  float* out = (float*)d_out;                 // [8,256,64,1024]

  char* ws = (char*)d_ws;
  u16* enc_bf = (u16*)ws;                     // 2,097,152 B
  u16* pred_bf = (u16*)(ws + 2097152);        //   524,288 B
  u16* We_bf = (u16*)(ws + 2621440);          //   655,360 B
  u16* Wp_bf = (u16*)(ws + 3276800);          //   655,360 B
  u16* Wo_bf = (u16*)(ws + 3932160);          // 1,310,720 B -> ends 5,242,880
  float* ep = (float*)(ws + 5242880);         // 5,242,880 B  [2048][640]
  float* pp = (float*)(ws + 10485760);        // 1,310,720 B  [512][640] -> ends 11,796,480
  u16* Wo_pk = (u16*)(ws + 11796480);         // 1,310,720 B packed fragments -> ends 13,107,200

  cast5_k<<<2048, 256, 0, stream>>>((const float4*)enc, (const float4*)pred,
                                    (const float4*)We, (const float4*)Wp,
                                    (const float4*)Wo, (ushort4*)ws);

  proj_k<<<dim3(16, 5), 256, 0, stream>>>(enc_bf, We_bf, ep);  // [2048][640]
  proj_k<<<dim3(4, 5), 256, 0, stream>>>(pred_bf, Wp_bf, pp);  // [512][640]
  pack_k<<<320, 256, 0, stream>>>(Wo_bf, Wo_pk);

  fused3_k<<<2048, 1024, 0, stream>>>(ep, pp, Wo_pk, out);
}